// Round 5
// baseline (2543.128 us; speedup 1.0000x reference)
//
#include <hip/hip_runtime.h>

// Problem constants (B=4, N=1024, DIM=1024, H=16, DH=64)
// Dtype model r5: tensor inputs fp32, masks int32 (r3-proven), d_out FP32
// (harness doc: "reference's OUTPUT dtype ... else float*"; JAX ref returns f32).
#define NTOK 4096            // B*N token rows
#define GQ 8                 // q-rows per attention block

// ---------------------------------------------------------------------------
// Mask canonicalization (kept; r3 proved masks arrive as int32 0/1).
// ---------------------------------------------------------------------------
__device__ __forceinline__ int mask_is_bytes(const int* p) {
  int bad = 0;
#pragma unroll
  for (int i = 0; i < 64; i++) bad |= (((unsigned int)p[i]) > 1u);
  return bad;
}

__global__ __launch_bounds__(256) void mask_prep(
    const int* __restrict__ srcQ, const int* __restrict__ srcK,
    int* __restrict__ dstQ, int* __restrict__ dstK)
{
  const int t = blockIdx.x * 256 + threadIdx.x;   // 0..4095
  const int bq = mask_is_bytes(srcQ);
  const int bk = mask_is_bytes(srcK);
  dstQ[t] = bq ? (int)((const unsigned char*)srcQ)[t] : srcQ[t];
  dstK[t] = bk ? (int)((const unsigned char*)srcK)[t] : srcK[t];
}

// ---------------------------------------------------------------------------
// fp32 vector GEMM: out[m,n] = sum_k X[m,k] * W[n,k].
// 64x64 tile, BK=16, 256 threads, 4x4 outputs/thread. Masked rows zeroed at store.
// ---------------------------------------------------------------------------
__global__ __launch_bounds__(256) void gemm_f32(
    const float* __restrict__ X, const float* __restrict__ W,
    const int* __restrict__ mask, float* __restrict__ out)
{
  __shared__ float sA[64][20];   // +4 pad keeps float4 alignment, breaks stride
  __shared__ float sB[64][20];
  const int t = threadIdx.x;
  const int bn = blockIdx.x, bm = blockIdx.y;
  const int r = t >> 2, cg = (t & 3) * 4;     // staging coords
  const int tx = t & 15, ty = t >> 4;         // compute coords
  float acc[4][4] = {};

  const float* ap = X + (size_t)(bm * 64 + r) * 1024 + cg;
  const float* bp = W + (size_t)(bn * 64 + r) * 1024 + cg;

  for (int kt = 0; kt < 64; kt++) {
    const float4 av = *(const float4*)(ap + kt * 16);
    const float4 bv = *(const float4*)(bp + kt * 16);
    __syncthreads();                          // prev iter's LDS reads done
    *(float4*)&sA[r][cg] = av;
    *(float4*)&sB[r][cg] = bv;
    __syncthreads();
#pragma unroll
    for (int kk = 0; kk < 16; kk += 4) {
      float4 a4[4], b4[4];
#pragma unroll
      for (int i = 0; i < 4; i++) a4[i] = *(const float4*)&sA[ty * 4 + i][kk];
#pragma unroll
      for (int j = 0; j < 4; j++) b4[j] = *(const float4*)&sB[tx * 4 + j][kk];
#pragma unroll
      for (int i = 0; i < 4; i++)
#pragma unroll
        for (int j = 0; j < 4; j++)
          acc[i][j] += a4[i].x * b4[j].x + a4[i].y * b4[j].y +
                       a4[i].z * b4[j].z + a4[i].w * b4[j].w;
    }
  }
#pragma unroll
  for (int i = 0; i < 4; i++) {
    const int row = bm * 64 + ty * 4 + i;
    const int msk = mask[row];
    float4 o;
    o.x = msk ? 0.f : acc[i][0];
    o.y = msk ? 0.f : acc[i][1];
    o.z = msk ? 0.f : acc[i][2];
    o.w = msk ? 0.f : acc[i][3];
    *(float4*)&out[(size_t)row * 1024 + bn * 64 + tx * 4] = o;
  }
}

// Same fp32 GEMM, epilogue: O2 = X1 + gelu_exact(X1 @ Wo^T).
__global__ __launch_bounds__(256) void gemm_wo_f32(
    const float* __restrict__ X1, const float* __restrict__ W,
    float* __restrict__ O2)
{
  __shared__ float sA[64][20];
  __shared__ float sB[64][20];
  const int t = threadIdx.x;
  const int bn = blockIdx.x, bm = blockIdx.y;
  const int r = t >> 2, cg = (t & 3) * 4;
  const int tx = t & 15, ty = t >> 4;
  float acc[4][4] = {};

  const float* ap = X1 + (size_t)(bm * 64 + r) * 1024 + cg;
  const float* bp = W + (size_t)(bn * 64 + r) * 1024 + cg;

  for (int kt = 0; kt < 64; kt++) {
    const float4 av = *(const float4*)(ap + kt * 16);
    const float4 bv = *(const float4*)(bp + kt * 16);
    __syncthreads();
    *(float4*)&sA[r][cg] = av;
    *(float4*)&sB[r][cg] = bv;
    __syncthreads();
#pragma unroll
    for (int kk = 0; kk < 16; kk += 4) {
      float4 a4[4], b4[4];
#pragma unroll
      for (int i = 0; i < 4; i++) a4[i] = *(const float4*)&sA[ty * 4 + i][kk];
#pragma unroll
      for (int j = 0; j < 4; j++) b4[j] = *(const float4*)&sB[tx * 4 + j][kk];
#pragma unroll
      for (int i = 0; i < 4; i++)
#pragma unroll
        for (int j = 0; j < 4; j++)
          acc[i][j] += a4[i].x * b4[j].x + a4[i].y * b4[j].y +
                       a4[i].z * b4[j].z + a4[i].w * b4[j].w;
    }
  }
#pragma unroll
  for (int i = 0; i < 4; i++) {
    const size_t idx = (size_t)(bm * 64 + ty * 4 + i) * 1024 + bn * 64 + tx * 4;
    const float4 x = *(const float4*)&X1[idx];
    float4 o;
    {
      const float h0 = acc[i][0], h1 = acc[i][1], h2 = acc[i][2], h3 = acc[i][3];
      o.x = x.x + 0.5f * h0 * (1.0f + erff(h0 * 0.70710678118654752f));
      o.y = x.y + 0.5f * h1 * (1.0f + erff(h1 * 0.70710678118654752f));
      o.z = x.z + 0.5f * h2 * (1.0f + erff(h2 * 0.70710678118654752f));
      o.w = x.w + 0.5f * h3 * (1.0f + erff(h3 * 0.70710678118654752f));
    }
    *(float4*)&O2[idx] = o;   // masked rows: X1=0 -> h=0 -> gelu=0 -> 0 (matches ref)
  }
}

// ---------------------------------------------------------------------------
// Attention: per block = 8 q-rows of one (b,h). Vector fp32.
// scores -> masked softmax (pad = maskQ|maskK) -> AV; writes O1 = Qp + attn
// (zeroed for masked q). Scores live in LDS S[8][1024]; S reused for partials.
// ---------------------------------------------------------------------------
__global__ __launch_bounds__(256) void attn_kernel(
    const float* __restrict__ Qp, const float* __restrict__ Kp,
    const float* __restrict__ Vp, const int* __restrict__ maskQ,
    const int* __restrict__ maskK, float* __restrict__ O1)
{
  __shared__ float Qt[GQ * 64];
  __shared__ float S[GQ * 1024];
  const int t = threadIdx.x;
  const int qt = blockIdx.x;                  // 0..127
  const int bh = blockIdx.y;                  // 0..63
  const int b = bh >> 4, h = bh & 15;
  const int q0 = qt * GQ;
  const size_t rowbase = (size_t)b * 1024;

  if (t < 128) {                              // load Q tile (8 x 64)
    const int i = t >> 4, d4 = (t & 15) * 4;
    *(float4*)&Qt[i * 64 + d4] =
        *(const float4*)&Qp[(rowbase + q0 + i) * 1024 + h * 64 + d4];
  }
  __syncthreads();

  {  // phase 1: scores for this thread's 4 consecutive k rows
    const int k0 = 4 * t;
    const float* kp = Kp + (rowbase + k0) * 1024 + h * 64;
    float acc[8][4] = {};
#pragma unroll
    for (int dd = 0; dd < 8; dd++) {
      const int d0 = dd * 8;
      float4 k0r[4], k1r[4];
#pragma unroll
      for (int j = 0; j < 4; j++) {
        k0r[j] = *(const float4*)(kp + j * 1024 + d0);
        k1r[j] = *(const float4*)(kp + j * 1024 + d0 + 4);
      }
#pragma unroll
      for (int i = 0; i < 8; i++) {
        const float4 qa = *(const float4*)&Qt[i * 64 + d0];
        const float4 qb = *(const float4*)&Qt[i * 64 + d0 + 4];
#pragma unroll
        for (int j = 0; j < 4; j++) {
          acc[i][j] += qa.x * k0r[j].x + qa.y * k0r[j].y + qa.z * k0r[j].z + qa.w * k0r[j].w +
                       qb.x * k1r[j].x + qb.y * k1r[j].y + qb.z * k1r[j].z + qb.w * k1r[j].w;
        }
      }
    }
    const int4 mk = *(const int4*)&maskK[b * 1024 + k0];
    const int mks[4] = {mk.x, mk.y, mk.z, mk.w};
#pragma unroll
    for (int i = 0; i < 8; i++) {
      float4 sv;
      sv.x = mks[0] ? -1e30f : acc[i][0] * 0.03125f;   // /sqrt(1024)
      sv.y = mks[1] ? -1e30f : acc[i][1] * 0.03125f;
      sv.z = mks[2] ? -1e30f : acc[i][2] * 0.03125f;
      sv.w = mks[3] ? -1e30f : acc[i][3] * 0.03125f;
      *(float4*)&S[i * 1024 + k0] = sv;
    }
  }
  __syncthreads();

  {  // phase 2: softmax per row (32 lanes per row)
    const int i = t >> 5, j = t & 31;
    float vals[32];
    float m = -1e30f;
#pragma unroll
    for (int n = 0; n < 32; n++) { vals[n] = S[i * 1024 + j + 32 * n]; m = fmaxf(m, vals[n]); }
#pragma unroll
    for (int off = 16; off >= 1; off >>= 1) m = fmaxf(m, __shfl_xor(m, off));
    float l = 0.0f;
#pragma unroll
    for (int n = 0; n < 32; n++) {
      const float e = (vals[n] <= -1e29f) ? 0.0f : __expf(vals[n] - m);
      vals[n] = e; l += e;
    }
#pragma unroll
    for (int off = 16; off >= 1; off >>= 1) l += __shfl_xor(l, off);
    const float inv = (l > 0.0f) ? 1.0f / l : 0.0f;   // all-masked row -> A = 0
#pragma unroll
    for (int n = 0; n < 32; n++) S[i * 1024 + j + 32 * n] = vals[n] * inv;
  }
  __syncthreads();

  const int dq = (t & 15) * 4;
  const int kg = t >> 4;                       // 16 k-groups of 64 k each
  {  // phase 3: AV partials; V streamed coalesced from global
    float4 acc4[8];
#pragma unroll
    for (int i = 0; i < 8; i++) acc4[i] = make_float4(0.f, 0.f, 0.f, 0.f);
    const float* vp = Vp + (rowbase + kg * 64) * 1024 + h * 64 + dq;
#pragma unroll 2
    for (int kq = 0; kq < 16; kq++) {
      float4 vr[4];
#pragma unroll
      for (int j = 0; j < 4; j++) vr[j] = *(const float4*)(vp + (kq * 4 + j) * 1024);
      const int kk = kg * 64 + kq * 4;
#pragma unroll
      for (int i = 0; i < 8; i++) {
        const float4 a = *(const float4*)&S[i * 1024 + kk];
        acc4[i].x += a.x * vr[0].x + a.y * vr[1].x + a.z * vr[2].x + a.w * vr[3].x;
        acc4[i].y += a.x * vr[0].y + a.y * vr[1].y + a.z * vr[2].y + a.w * vr[3].y;
        acc4[i].z += a.x * vr[0].z + a.y * vr[1].z + a.z * vr[2].z + a.w * vr[3].z;
        acc4[i].w += a.x * vr[0].w + a.y * vr[1].w + a.z * vr[2].w + a.w * vr[3].w;
      }
    }
    __syncthreads();                           // all S reads done; reuse S for partials
#pragma unroll
    for (int i = 0; i < 8; i++)
      *(float4*)&S[(kg * 8 + i) * 64 + dq] = acc4[i];   // 16*8*64 = 8192 floats
  }
  __syncthreads();

  for (int o = t; o < 512; o += 256) {         // reduce 16 partials, add residual Qp
    const int i = o >> 6, d = o & 63;
    float ssum = 0.0f;
#pragma unroll
    for (int g = 0; g < 16; g++) ssum += S[(g * 8 + i) * 64 + d];
    const size_t gi = (rowbase + q0 + i) * 1024 + h * 64 + d;
    O1[gi] = (maskQ[b * 1024 + q0 + i] != 0) ? 0.0f : (Qp[gi] + ssum);
  }
}

// ---------------------------------------------------------------------------
// LayerNorm (one row of 1024 per block), fp32 in/out. Used for BOTH LN1 and
// LN2 (d_out is fp32 per the reference's output dtype).
// ---------------------------------------------------------------------------
__device__ __forceinline__ void ln_stats(float4 x, int t, float* mean, float* rinv) {
  float s = x.x + x.y + x.z + x.w;
  float s2 = x.x * x.x + x.y * x.y + x.z * x.z + x.w * x.w;
#pragma unroll
  for (int off = 32; off >= 1; off >>= 1) { s += __shfl_xor(s, off); s2 += __shfl_xor(s2, off); }
  __shared__ float red[8];
  __shared__ float sm[2];
  const int wv = t >> 6, lane = t & 63;
  if (lane == 0) { red[wv] = s; red[4 + wv] = s2; }
  __syncthreads();
  if (t == 0) {
    const float S = red[0] + red[1] + red[2] + red[3];
    const float S2 = red[4] + red[5] + red[6] + red[7];
    const float m = S * (1.0f / 1024.0f);
    const float v = S2 * (1.0f / 1024.0f) - m * m;
    sm[0] = m; sm[1] = rsqrtf(v + 1e-5f);
  }
  __syncthreads();
  *mean = sm[0]; *rinv = sm[1];
}

__global__ __launch_bounds__(256) void ln_f32(
    const float* __restrict__ X, const float* __restrict__ g,
    const float* __restrict__ bta, const int* __restrict__ mask,
    float* __restrict__ out)
{
  const int r = blockIdx.x, t = threadIdx.x, c = 4 * t;
  const float4 x = *(const float4*)&X[(size_t)r * 1024 + c];
  float mean, ri;
  ln_stats(x, t, &mean, &ri);
  const int msk = mask[r];
  const float4 gg = *(const float4*)&g[c];
  const float4 bb = *(const float4*)&bta[c];
  float4 o;
  o.x = msk ? 0.f : (x.x - mean) * ri * gg.x + bb.x;
  o.y = msk ? 0.f : (x.y - mean) * ri * gg.y + bb.y;
  o.z = msk ? 0.f : (x.z - mean) * ri * gg.z + bb.z;
  o.w = msk ? 0.f : (x.w - mean) * ri * gg.w + bb.w;
  *(float4*)&out[(size_t)r * 1024 + c] = o;
}

// ---------------------------------------------------------------------------
extern "C" void kernel_launch(void* const* d_in, const int* in_sizes, int n_in,
                              void* d_out, int out_size, void* d_ws, size_t ws_size,
                              hipStream_t stream)
{
  const float* Q  = (const float*)d_in[0];
  const float* K  = (const float*)d_in[1];
  const float* V  = (const float*)d_in[2];
  const float* Wq = (const float*)d_in[3];
  const float* Wk = (const float*)d_in[4];
  const float* Wv = (const float*)d_in[5];
  const float* Wo = (const float*)d_in[6];
  const float* g1 = (const float*)d_in[7];
  const float* b1 = (const float*)d_in[8];
  const float* g2 = (const float*)d_in[9];
  const float* b2 = (const float*)d_in[10];
  float* out = (float*)d_out;                  // fp32 output (reference dtype)

  float* w = (float*)d_ws;
  const size_t MN = (size_t)NTOK * 1024;       // 4M floats = 16 MB per buffer
  float* Qp = w;                               // peak ws usage: 64 MB + 32 KB
  float* Kp = w + MN;
  float* Vp = w + 2 * MN;
  float* O1 = w + 3 * MN;
  float* X1 = Kp;                              // Kp dead after attn
  float* O2 = Vp;                              // Vp dead after attn
  int* mQ = (int*)(w + 4 * MN);                // canonical int32 masks
  int* mK = mQ + NTOK;

  const dim3 gg(16, 64), bb(256);
  mask_prep<<<dim3(16), bb, 0, stream>>>((const int*)d_in[11], (const int*)d_in[12], mQ, mK);
  gemm_f32<<<gg, bb, 0, stream>>>(Q, Wq, mQ, Qp);
  gemm_f32<<<gg, bb, 0, stream>>>(K, Wk, mK, Kp);
  gemm_f32<<<gg, bb, 0, stream>>>(V, Wv, mK, Vp);
  attn_kernel<<<dim3(128, 64), bb, 0, stream>>>(Qp, Kp, Vp, mQ, mK, O1);
  ln_f32<<<dim3(4096), bb, 0, stream>>>(O1, g1, b1, mQ, X1);
  gemm_wo_f32<<<gg, bb, 0, stream>>>(X1, Wo, O2);
  ln_f32<<<dim3(4096), bb, 0, stream>>>(O2, g2, b2, mQ, out);
}

// Round 6
// 355.107 us; speedup vs baseline: 7.1616x; 7.1616x over previous
//
#include <hip/hip_runtime.h>

// Problem constants (B=4, N=1024, DIM=1024, H=16, DH=64)
// Dtype model (r5-proven): tensor inputs fp32, masks int32, d_out fp32.
#define NTOK 4096
#define AST 72   // attn LDS row stride in halves (144 B: b64-aligned, 2-way-conflict-free)

typedef _Float16 half4 __attribute__((ext_vector_type(4)));
typedef _Float16 half8 __attribute__((ext_vector_type(8)));
typedef float floatx4 __attribute__((ext_vector_type(4)));

__device__ __forceinline__ half8 cvt8(float4 a, float4 b) {
  half8 h;
  h[0] = (_Float16)a.x; h[1] = (_Float16)a.y; h[2] = (_Float16)a.z; h[3] = (_Float16)a.w;
  h[4] = (_Float16)b.x; h[5] = (_Float16)b.y; h[6] = (_Float16)b.z; h[7] = (_Float16)b.w;
  return h;
}
// two ds_read_b64 (stride-72 rows are only 8B-aligned; avoids misaligned b128)
__device__ __forceinline__ half8 lds8(const _Float16* p) {
  const half4 lo = *(const half4*)p;
  const half4 hi = *(const half4*)(p + 4);
  half8 r;
  r[0] = lo[0]; r[1] = lo[1]; r[2] = lo[2]; r[3] = lo[3];
  r[4] = hi[0]; r[5] = hi[1]; r[6] = hi[2]; r[7] = hi[3];
  return r;
}

// ---------------------------------------------------------------------------
// Mask canonicalization (r3 proved masks arrive int32; keep for robustness).
// ---------------------------------------------------------------------------
__device__ __forceinline__ int mask_is_bytes(const int* p) {
  int bad = 0;
#pragma unroll
  for (int i = 0; i < 64; i++) bad |= (((unsigned int)p[i]) > 1u);
  return bad;
}

__global__ __launch_bounds__(256) void mask_prep(
    const int* __restrict__ srcQ, const int* __restrict__ srcK,
    int* __restrict__ dstQ, int* __restrict__ dstK)
{
  const int t = blockIdx.x * 256 + threadIdx.x;
  const int bq = mask_is_bytes(srcQ);
  const int bk = mask_is_bytes(srcK);
  dstQ[t] = bq ? (int)((const unsigned char*)srcQ)[t] : srcQ[t];
  dstK[t] = bk ? (int)((const unsigned char*)srcK)[t] : srcK[t];
}

// ---------------------------------------------------------------------------
// f16-MFMA GEMM (r2 structure — proven numerically equivalent to fp32 GEMM):
// out[m,n] = sum_k X[m,k]*W[n,k]; 64x64 tile, BK=32, 4 waves.
// mfma_f32_16x16x32_f16: a[j]=A[m=lane&15][k=quad*8+j]; b[j]=B[n=lane&15][k=quad*8+j];
// C/D: row=quad*4+reg, col=lane&15. sA/sB stride 40 halves = 80 B (16B-aligned, 2-way free).
// ---------------------------------------------------------------------------
__global__ __launch_bounds__(256) void gemm_proj(
    const float* __restrict__ X, const float* __restrict__ W,
    const int* __restrict__ mask, float* __restrict__ out)
{
  __shared__ _Float16 sA[64 * 40];
  __shared__ _Float16 sB[64 * 40];
  const int t = threadIdx.x;
  const int bn = blockIdx.x, bm = blockIdx.y;
  const int lane = t & 63, wv = t >> 6;
  const int r = t >> 2, cg = (t & 3) * 8;
  const int qd = lane >> 4;
  floatx4 acc[4] = {};

  const float* ap = X + (size_t)(bm * 64 + r) * 1024 + cg;
  const float* bp = W + (size_t)(bn * 64 + r) * 1024 + cg;

  for (int kt = 0; kt < 32; kt++) {
    const float4 a0 = *(const float4*)(ap + kt * 32);
    const float4 a1 = *(const float4*)(ap + kt * 32 + 4);
    const float4 b0 = *(const float4*)(bp + kt * 32);
    const float4 b1 = *(const float4*)(bp + kt * 32 + 4);
    const half8 ha = cvt8(a0, a1);
    const half8 hb = cvt8(b0, b1);
    __syncthreads();
    *(half8*)&sA[r * 40 + cg] = ha;
    *(half8*)&sB[r * 40 + cg] = hb;
    __syncthreads();
    const half8 af = *(const half8*)&sA[(wv * 16 + (lane & 15)) * 40 + qd * 8];
#pragma unroll
    for (int s = 0; s < 4; s++) {
      const half8 bf_ = *(const half8*)&sB[(s * 16 + (lane & 15)) * 40 + qd * 8];
      acc[s] = __builtin_amdgcn_mfma_f32_16x16x32_f16(af, bf_, acc[s], 0, 0, 0);
    }
  }
  const int m0 = bm * 64 + wv * 16 + qd * 4;
  const int n0 = bn * 64 + (lane & 15);
#pragma unroll
  for (int s = 0; s < 4; s++) {
    const int col = n0 + s * 16;
#pragma unroll
    for (int rr = 0; rr < 4; rr++) {
      const int row = m0 + rr;
      out[(size_t)row * 1024 + col] = (mask[row] != 0) ? 0.0f : acc[s][rr];
    }
  }
}

// Same GEMM, epilogue: O2 = X1 + gelu_exact(X1 @ Wo^T).
__global__ __launch_bounds__(256) void gemm_wo(
    const float* __restrict__ X1, const float* __restrict__ W,
    float* __restrict__ O2)
{
  __shared__ _Float16 sA[64 * 40];
  __shared__ _Float16 sB[64 * 40];
  const int t = threadIdx.x;
  const int bn = blockIdx.x, bm = blockIdx.y;
  const int lane = t & 63, wv = t >> 6;
  const int r = t >> 2, cg = (t & 3) * 8;
  const int qd = lane >> 4;
  floatx4 acc[4] = {};

  const float* ap = X1 + (size_t)(bm * 64 + r) * 1024 + cg;
  const float* bp = W + (size_t)(bn * 64 + r) * 1024 + cg;

  for (int kt = 0; kt < 32; kt++) {
    const float4 a0 = *(const float4*)(ap + kt * 32);
    const float4 a1 = *(const float4*)(ap + kt * 32 + 4);
    const float4 b0 = *(const float4*)(bp + kt * 32);
    const float4 b1 = *(const float4*)(bp + kt * 32 + 4);
    const half8 ha = cvt8(a0, a1);
    const half8 hb = cvt8(b0, b1);
    __syncthreads();
    *(half8*)&sA[r * 40 + cg] = ha;
    *(half8*)&sB[r * 40 + cg] = hb;
    __syncthreads();
    const half8 af = *(const half8*)&sA[(wv * 16 + (lane & 15)) * 40 + qd * 8];
#pragma unroll
    for (int s = 0; s < 4; s++) {
      const half8 bf_ = *(const half8*)&sB[(s * 16 + (lane & 15)) * 40 + qd * 8];
      acc[s] = __builtin_amdgcn_mfma_f32_16x16x32_f16(af, bf_, acc[s], 0, 0, 0);
    }
  }
  const int m0 = bm * 64 + wv * 16 + qd * 4;
  const int n0 = bn * 64 + (lane & 15);
#pragma unroll
  for (int s = 0; s < 4; s++) {
    const int col = n0 + s * 16;
#pragma unroll
    for (int rr = 0; rr < 4; rr++) {
      const size_t idx = (size_t)(m0 + rr) * 1024 + col;
      const float hv = acc[s][rr];
      const float ge = 0.5f * hv * (1.0f + erff(hv * 0.70710678118654752f));
      O2[idx] = X1[idx] + ge;
    }
  }
}

// ---------------------------------------------------------------------------
// MFMA flash attention. Block = 64 q-rows of one (b,h); 4 waves x 16 rows.
// Per 64-k tile: stage K (row-major f16) and V^T into LDS, S=Q.K^T via MFMA,
// online softmax in C-layout regs (16-lane shuffle reduce), P via wave-private
// LDS round-trip (C-layout -> A-layout; same-wave DS ordering, no barrier),
// O += P.V via MFMA. Mask: additive bias + exact p=0 for s<=-1e20.
// Epilogue: O1 = maskQ ? 0 : Qp + O/l.
// ---------------------------------------------------------------------------
__global__ __launch_bounds__(256) void attn_mfma(
    const float* __restrict__ Qp, const float* __restrict__ Kp,
    const float* __restrict__ Vp, const int* __restrict__ maskQ,
    const int* __restrict__ maskK, float* __restrict__ O1)
{
  __shared__ _Float16 sK [64 * AST];
  __shared__ _Float16 sVt[64 * AST];
  __shared__ _Float16 sQP[64 * AST];   // Q tile at start; per-wave P tiles in loop
  __shared__ float bias[1024];

  const int t = threadIdx.x;
  const int qt = blockIdx.x;           // 0..15
  const int bh = blockIdx.y;           // 0..63
  const int b = bh >> 4, h = bh & 15;
  const int q0 = qt * 64;
  const size_t base = (size_t)b * 1024;
  const int wv = t >> 6, lane = t & 63, quad = lane >> 4, l16 = lane & 15;
  const int r = t >> 2, c0 = (t & 3) * 16;

  for (int i = t; i < 1024; i += 256)
    bias[i] = maskK[b * 1024 + i] ? -1e30f : 0.0f;

  {  // stage Q tile (64 x 64 fp32 -> f16)
    const float* qp = Qp + (base + q0 + r) * 1024 + h * 64 + c0;
#pragma unroll
    for (int j = 0; j < 4; j++) {
      const float4 v = *(const float4*)(qp + j * 4);
      half4 hq; hq[0] = (_Float16)v.x; hq[1] = (_Float16)v.y;
      hq[2] = (_Float16)v.z; hq[3] = (_Float16)v.w;
      *(half4*)&sQP[r * AST + c0 + j * 4] = hq;
    }
  }
  __syncthreads();

  const half8 aq0 = lds8(&sQP[(wv * 16 + l16) * AST + quad * 8]);
  const half8 aq1 = lds8(&sQP[(wv * 16 + l16) * AST + 32 + quad * 8]);

  float m_i[4], l_i[4];
  floatx4 acc_o[4] = {};
#pragma unroll
  for (int i = 0; i < 4; i++) { m_i[i] = -1e30f; l_i[i] = 0.0f; }

  for (int kt = 0; kt < 16; kt++) {
    __syncthreads();                   // prev iter's LDS frag reads done
    {
      const float* kp = Kp + (base + kt * 64 + r) * 1024 + h * 64 + c0;
      const float* vp = Vp + (base + kt * 64 + r) * 1024 + h * 64 + c0;
#pragma unroll
      for (int j = 0; j < 4; j++) {
        const float4 kv = *(const float4*)(kp + j * 4);
        half4 hk; hk[0] = (_Float16)kv.x; hk[1] = (_Float16)kv.y;
        hk[2] = (_Float16)kv.z; hk[3] = (_Float16)kv.w;
        *(half4*)&sK[r * AST + c0 + j * 4] = hk;
        const float4 vv = *(const float4*)(vp + j * 4);
        const int c = c0 + j * 4;
        sVt[(c + 0) * AST + r] = (_Float16)vv.x;
        sVt[(c + 1) * AST + r] = (_Float16)vv.y;
        sVt[(c + 2) * AST + r] = (_Float16)vv.z;
        sVt[(c + 3) * AST + r] = (_Float16)vv.w;
      }
    }
    __syncthreads();

    // S = Q.K^T (wave: 16q x 64k), then scale + mask-bias
    floatx4 s[4] = {};
#pragma unroll
    for (int nt = 0; nt < 4; nt++) {
      const half8 bk0 = lds8(&sK[(nt * 16 + l16) * AST + quad * 8]);
      const half8 bk1 = lds8(&sK[(nt * 16 + l16) * AST + 32 + quad * 8]);
      s[nt] = __builtin_amdgcn_mfma_f32_16x16x32_f16(aq0, bk0, s[nt], 0, 0, 0);
      s[nt] = __builtin_amdgcn_mfma_f32_16x16x32_f16(aq1, bk1, s[nt], 0, 0, 0);
    }
#pragma unroll
    for (int nt = 0; nt < 4; nt++) {
      const float bv = bias[kt * 64 + nt * 16 + l16];
#pragma unroll
      for (int rr = 0; rr < 4; rr++)
        s[nt][rr] = s[nt][rr] * 0.03125f + bv;   // /sqrt(1024)
    }

    // online softmax (rows = quad*4+rr; cols spread over 16 lanes x 4 nt)
    float mn[4], alpha[4], rsum[4];
#pragma unroll
    for (int rr = 0; rr < 4; rr++) {
      float mx = fmaxf(fmaxf(s[0][rr], s[1][rr]), fmaxf(s[2][rr], s[3][rr]));
#pragma unroll
      for (int off = 8; off >= 1; off >>= 1) mx = fmaxf(mx, __shfl_xor(mx, off));
      mn[rr] = fmaxf(m_i[rr], mx);
      alpha[rr] = __expf(m_i[rr] - mn[rr]);
      m_i[rr] = mn[rr];
      rsum[rr] = 0.0f;
    }
#pragma unroll
    for (int nt = 0; nt < 4; nt++)
#pragma unroll
      for (int rr = 0; rr < 4; rr++) {
        const float sv = s[nt][rr];
        const float p = (sv <= -1e20f) ? 0.0f : __expf(sv - mn[rr]);
        s[nt][rr] = p;
        rsum[rr] += p;
      }
#pragma unroll
    for (int rr = 0; rr < 4; rr++) {
#pragma unroll
      for (int off = 8; off >= 1; off >>= 1) rsum[rr] += __shfl_xor(rsum[rr], off);
      l_i[rr] = l_i[rr] * alpha[rr] + rsum[rr];
    }
#pragma unroll
    for (int nt = 0; nt < 4; nt++)
#pragma unroll
      for (int rr = 0; rr < 4; rr++)
        acc_o[nt][rr] *= alpha[rr];

    // P: C-layout -> wave-private LDS rows -> A-layout frags
#pragma unroll
    for (int nt = 0; nt < 4; nt++)
#pragma unroll
      for (int rr = 0; rr < 4; rr++)
        sQP[(wv * 16 + quad * 4 + rr) * AST + nt * 16 + l16] = (_Float16)s[nt][rr];

    const half8 ap0 = lds8(&sQP[(wv * 16 + l16) * AST + quad * 8]);
    const half8 ap1 = lds8(&sQP[(wv * 16 + l16) * AST + 32 + quad * 8]);
#pragma unroll
    for (int nt = 0; nt < 4; nt++) {
      const half8 bv0 = lds8(&sVt[(nt * 16 + l16) * AST + quad * 8]);
      const half8 bv1 = lds8(&sVt[(nt * 16 + l16) * AST + 32 + quad * 8]);
      acc_o[nt] = __builtin_amdgcn_mfma_f32_16x16x32_f16(ap0, bv0, acc_o[nt], 0, 0, 0);
      acc_o[nt] = __builtin_amdgcn_mfma_f32_16x16x32_f16(ap1, bv1, acc_o[nt], 0, 0, 0);
    }
  }

  // epilogue: O1 = maskQ ? 0 : Qp + O/l
#pragma unroll
  for (int rr = 0; rr < 4; rr++) {
    const int row = q0 + wv * 16 + quad * 4 + rr;
    const float inv = (l_i[rr] > 0.0f) ? 1.0f / l_i[rr] : 0.0f;
    const int mq = maskQ[b * 1024 + row];
#pragma unroll
    for (int nt = 0; nt < 4; nt++) {
      const size_t gi = (base + row) * 1024 + h * 64 + nt * 16 + l16;
      O1[gi] = mq ? 0.0f : (Qp[gi] + acc_o[nt][rr] * inv);
    }
  }
}

// ---------------------------------------------------------------------------
// LayerNorm (one row of 1024 per block), fp32 in/out.
// ---------------------------------------------------------------------------
__device__ __forceinline__ void ln_stats(float4 x, int t, float* mean, float* rinv) {
  float s = x.x + x.y + x.z + x.w;
  float s2 = x.x * x.x + x.y * x.y + x.z * x.z + x.w * x.w;
#pragma unroll
  for (int off = 32; off >= 1; off >>= 1) { s += __shfl_xor(s, off); s2 += __shfl_xor(s2, off); }
  __shared__ float red[8];
  __shared__ float sm[2];
  const int wv = t >> 6, lane = t & 63;
  if (lane == 0) { red[wv] = s; red[4 + wv] = s2; }
  __syncthreads();
  if (t == 0) {
    const float S = red[0] + red[1] + red[2] + red[3];
    const float S2 = red[4] + red[5] + red[6] + red[7];
    const float m = S * (1.0f / 1024.0f);
    const float v = S2 * (1.0f / 1024.0f) - m * m;
    sm[0] = m; sm[1] = rsqrtf(v + 1e-5f);
  }
  __syncthreads();
  *mean = sm[0]; *rinv = sm[1];
}

__global__ __launch_bounds__(256) void ln_f32(
    const float* __restrict__ X, const float* __restrict__ g,
    const float* __restrict__ bta, const int* __restrict__ mask,
    float* __restrict__ out)
{
  const int rr = blockIdx.x, t = threadIdx.x, c = 4 * t;
  const float4 x = *(const float4*)&X[(size_t)rr * 1024 + c];
  float mean, ri;
  ln_stats(x, t, &mean, &ri);
  const int msk = mask[rr];
  const float4 gg = *(const float4*)&g[c];
  const float4 bb = *(const float4*)&bta[c];
  float4 o;
  o.x = msk ? 0.f : (x.x - mean) * ri * gg.x + bb.x;
  o.y = msk ? 0.f : (x.y - mean) * ri * gg.y + bb.y;
  o.z = msk ? 0.f : (x.z - mean) * ri * gg.z + bb.z;
  o.w = msk ? 0.f : (x.w - mean) * ri * gg.w + bb.w;
  *(float4*)&out[(size_t)rr * 1024 + c] = o;
}

// ---------------------------------------------------------------------------
extern "C" void kernel_launch(void* const* d_in, const int* in_sizes, int n_in,
                              void* d_out, int out_size, void* d_ws, size_t ws_size,
                              hipStream_t stream)
{
  const float* Q  = (const float*)d_in[0];
  const float* K  = (const float*)d_in[1];
  const float* V  = (const float*)d_in[2];
  const float* Wq = (const float*)d_in[3];
  const float* Wk = (const float*)d_in[4];
  const float* Wv = (const float*)d_in[5];
  const float* Wo = (const float*)d_in[6];
  const float* g1 = (const float*)d_in[7];
  const float* b1 = (const float*)d_in[8];
  const float* g2 = (const float*)d_in[9];
  const float* b2 = (const float*)d_in[10];
  float* out = (float*)d_out;

  float* w = (float*)d_ws;
  const size_t MN = (size_t)NTOK * 1024;       // 16 MB per buffer
  float* Qp = w;
  float* Kp = w + MN;
  float* Vp = w + 2 * MN;
  float* O1 = w + 3 * MN;
  float* X1 = Kp;                              // Kp dead after attn
  float* O2 = Vp;                              // Vp dead after attn
  int* mQ = (int*)(w + 4 * MN);
  int* mK = mQ + NTOK;

  const dim3 gg(16, 64), bb(256);
  mask_prep<<<dim3(16), bb, 0, stream>>>((const int*)d_in[11], (const int*)d_in[12], mQ, mK);
  gemm_proj<<<gg, bb, 0, stream>>>(Q, Wq, mQ, Qp);
  gemm_proj<<<gg, bb, 0, stream>>>(K, Wk, mK, Kp);
  gemm_proj<<<gg, bb, 0, stream>>>(V, Wv, mK, Vp);
  attn_mfma<<<dim3(16, 64), bb, 0, stream>>>(Qp, Kp, Vp, mQ, mK, O1);
  ln_f32<<<dim3(4096), bb, 0, stream>>>(O1, g1, b1, mQ, X1);
  gemm_wo<<<gg, bb, 0, stream>>>(X1, Wo, O2);
  ln_f32<<<dim3(4096), bb, 0, stream>>>(O2, g2, b2, mQ, out);
}